// Round 1
// baseline (753.041 us; speedup 1.0000x reference)
//
#include <hip/hip_runtime.h>

#define N_NODES 100000
#define N_EDGES 1600000

constexpr int BM = 128, BN = 128, BK = 16;

// ---------------- GEMM: C[M x 128] = A[M x K] @ W[K x 128] + bias ----------------
// 128x128 tile, 256 threads, 8x8 register blocking. fp32 (no fp32 MFMA on CDNA4).
template<int K>
__global__ __launch_bounds__(256)
void gemm_bias(const float* __restrict__ A, const float* __restrict__ W,
               const float* __restrict__ bias, float* __restrict__ C, int M)
{
    __shared__ float As[BK][BM + 4];   // A tile, transposed: As[k][m]; +4 pad -> 2-way max on store
    __shared__ float Bs[BK][BN + 4];
    const int t  = threadIdx.x;
    const int m0 = blockIdx.x * BM;
    const int tc = t & 15;        // col group: cols tc*8..tc*8+7
    const int tr = t >> 4;        // row group: rows tr*8..tr*8+7
    const int a_r = t >> 2;       // staging: row 0..63 (two passes)
    const int a_k = (t & 3) << 2; // staging: k offset 0/4/8/12
    const int b_k = t >> 5;       // staging: B row 0..7 (two passes)
    const int b_c = (t & 31) << 2;

    float acc[8][8] = {};

    for (int k0 = 0; k0 < K; k0 += BK) {
        #pragma unroll
        for (int h = 0; h < 2; ++h) {
            int m  = m0 + a_r + h * 64;
            int ms = m < M ? m : M - 1;              // clamp (dup loads harmless; stores guarded)
            float4 v = *(const float4*)(A + (size_t)ms * K + k0 + a_k);
            As[a_k + 0][a_r + h * 64] = v.x;
            As[a_k + 1][a_r + h * 64] = v.y;
            As[a_k + 2][a_r + h * 64] = v.z;
            As[a_k + 3][a_r + h * 64] = v.w;
        }
        #pragma unroll
        for (int h = 0; h < 2; ++h) {
            int kk = b_k + h * 8;
            *(float4*)&Bs[kk][b_c] = *(const float4*)(W + (size_t)(k0 + kk) * BN + b_c);
        }
        __syncthreads();
        #pragma unroll
        for (int k = 0; k < BK; ++k) {
            float a[8], b[8];
            *(float4*)&a[0] = *(const float4*)&As[k][tr * 8];
            *(float4*)&a[4] = *(const float4*)&As[k][tr * 8 + 4];
            *(float4*)&b[0] = *(const float4*)&Bs[k][tc * 8];
            *(float4*)&b[4] = *(const float4*)&Bs[k][tc * 8 + 4];
            #pragma unroll
            for (int i = 0; i < 8; ++i)
                #pragma unroll
                for (int j = 0; j < 8; ++j)
                    acc[i][j] = fmaf(a[i], b[j], acc[i][j]);
        }
        __syncthreads();
    }

    float bv[8];
    *(float4*)&bv[0] = *(const float4*)(bias + tc * 8);
    *(float4*)&bv[4] = *(const float4*)(bias + tc * 8 + 4);
    for (int i = 0; i < 8; ++i) {
        int m = m0 + tr * 8 + i;
        if (m < M) {
            float o[8];
            #pragma unroll
            for (int j = 0; j < 8; ++j) o[j] = acc[i][j] + bv[j];
            *(float4*)(C + (size_t)m * BN + tc * 8)     = *(float4*)&o[0];
            *(float4*)(C + (size_t)m * BN + tc * 8 + 4) = *(float4*)&o[4];
        }
    }
}

// ---------------- CSR build ----------------
__global__ __launch_bounds__(256)
void hist_rows(const int* __restrict__ row, int* __restrict__ cnt, int E)
{
    int e = blockIdx.x * 256 + threadIdx.x;
    if (e < E) atomicAdd(&cnt[row[e]], 1);
}

// block-level exclusive scan; 2048 items / block
__global__ __launch_bounds__(256)
void scan_a(const int* __restrict__ cnt, int* __restrict__ rowptr,
            int* __restrict__ bsum, int n)
{
    __shared__ int sd[256];
    int t = threadIdx.x;
    int base = blockIdx.x * 2048 + t * 8;
    int v[8]; int run = 0;
    #pragma unroll
    for (int j = 0; j < 8; ++j) {
        int idx = base + j;
        int c = (idx < n) ? cnt[idx] : 0;
        v[j] = run; run += c;
    }
    sd[t] = run;
    __syncthreads();
    for (int off = 1; off < 256; off <<= 1) {   // Hillis-Steele inclusive
        int x = (t >= off) ? sd[t - off] : 0;
        __syncthreads();
        sd[t] += x;
        __syncthreads();
    }
    int toff = sd[t] - run;                      // exclusive offset for this thread
    if (t == 255) bsum[blockIdx.x] = sd[255];
    #pragma unroll
    for (int j = 0; j < 8; ++j) {
        int idx = base + j;
        if (idx < n) rowptr[idx] = toff + v[j];
    }
}

__global__ void scan_b(int* bsum, int nb)
{
    if (threadIdx.x == 0) {
        int run = 0;
        for (int i = 0; i < nb; ++i) { int x = bsum[i]; bsum[i] = run; run += x; }
    }
}

__global__ __launch_bounds__(256)
void scan_c(int* __restrict__ rowptr, const int* __restrict__ bsum,
            int* __restrict__ fill, int n, int E)
{
    int i = blockIdx.x * 256 + threadIdx.x;
    if (i < n) {
        int v = rowptr[i] + bsum[i >> 11];   // 2048 items per scan_a block
        rowptr[i] = v;
        fill[i] = v;
    }
    if (i == 0) rowptr[n] = E;
}

__global__ __launch_bounds__(256)
void scatter_edges(const int* __restrict__ row, const int* __restrict__ col,
                   const float* __restrict__ vals, int* __restrict__ fill,
                   int* __restrict__ ecol, float* __restrict__ eval, int E)
{
    int e = blockIdx.x * 256 + threadIdx.x;
    if (e < E) {
        int r = row[e];
        int pos = atomicAdd(&fill[r], 1);
        ecol[pos] = col[e];
        eval[pos] = vals[e];
    }
}

// ---------------- SpMM (pull, CSR): out[i] = sum_e val_e * H[col_e] ----------------
// one wave per node; 64 lanes x float2 = 512B row; no fp atomics, coalesced store
__global__ __launch_bounds__(256)
void spmm_csr(const int* __restrict__ rowptr, const int* __restrict__ ecol,
              const float* __restrict__ eval, const float* __restrict__ H,
              float* __restrict__ out, int n, int do_relu)
{
    int wid  = (blockIdx.x * 256 + threadIdx.x) >> 6;
    int lane = threadIdx.x & 63;
    if (wid >= n) return;
    int s = rowptr[wid], e = rowptr[wid + 1];
    const float2* Hp = (const float2*)H;
    float2 acc = make_float2(0.f, 0.f);
    int p = s;
    for (; p + 2 <= e; p += 2) {                 // 2x unroll for gather ILP
        float v0 = eval[p], v1 = eval[p + 1];
        int   c0 = ecol[p], c1 = ecol[p + 1];
        float2 h0 = Hp[(size_t)c0 * 64 + lane];
        float2 h1 = Hp[(size_t)c1 * 64 + lane];
        acc.x = fmaf(v0, h0.x, acc.x); acc.y = fmaf(v0, h0.y, acc.y);
        acc.x = fmaf(v1, h1.x, acc.x); acc.y = fmaf(v1, h1.y, acc.y);
    }
    if (p < e) {
        float v = eval[p]; int c = ecol[p];
        float2 h = Hp[(size_t)c * 64 + lane];
        acc.x = fmaf(v, h.x, acc.x); acc.y = fmaf(v, h.y, acc.y);
    }
    if (do_relu) { acc.x = fmaxf(acc.x, 0.f); acc.y = fmaxf(acc.y, 0.f); }
    ((float2*)out)[(size_t)wid * 64 + lane] = acc;
}

// ---------------- launch ----------------
extern "C" void kernel_launch(void* const* d_in, const int* in_sizes, int n_in,
                              void* d_out, int out_size, void* d_ws, size_t ws_size,
                              hipStream_t stream)
{
    const float* X    = (const float*)d_in[0];
    const float* W1   = (const float*)d_in[1];
    const float* b1   = (const float*)d_in[2];
    const float* W2   = (const float*)d_in[3];
    const float* b2   = (const float*)d_in[4];
    const float* vals = (const float*)d_in[5];
    const int*   row  = (const int*)d_in[6];
    const int*   col  = (const int*)d_in[7];
    float* out = (float*)d_out;

    char* ws = (char*)d_ws;
    size_t off = 0;
    auto alloc = [&](size_t bytes) -> void* {
        void* p = ws + off;
        off += (bytes + 511) & ~(size_t)511;
        return p;
    };
    float* Y1     = (float*)alloc((size_t)N_NODES * 128 * 4); // XW1+b1, later HW2+b2
    float* Hbuf   = (float*)alloc((size_t)N_NODES * 128 * 4); // relu(spmm1)
    int*   rowptr = (int*)  alloc((size_t)(N_NODES + 1) * 4);
    int*   fill   = (int*)  alloc((size_t)N_NODES * 4);       // counts, then cursors
    int*   ecol   = (int*)  alloc((size_t)N_EDGES * 4);
    float* ev     = (float*)alloc((size_t)N_EDGES * 4);
    int*   bsum   = (int*)  alloc(512);

    // --- CSR build (row/col/vals fixed, but rebuilt every call: same work per call) ---
    hipMemsetAsync(fill, 0, (size_t)N_NODES * 4, stream);
    hist_rows<<<(N_EDGES + 255) / 256, 256, 0, stream>>>(row, fill, N_EDGES);
    const int nb = (N_NODES + 2047) / 2048; // 49
    scan_a<<<nb, 256, 0, stream>>>(fill, rowptr, bsum, N_NODES);
    scan_b<<<1, 64, 0, stream>>>(bsum, nb);
    scan_c<<<(N_NODES + 255) / 256, 256, 0, stream>>>(rowptr, bsum, fill, N_NODES, N_EDGES);
    scatter_edges<<<(N_EDGES + 255) / 256, 256, 0, stream>>>(row, col, vals, fill, ecol, ev, N_EDGES);

    // --- layer 1: Y1 = X@W1+b1 ; H = relu(A@Y1) ---
    const int gblocks = (N_NODES + BM - 1) / BM; // 782
    gemm_bias<256><<<gblocks, 256, 0, stream>>>(X, W1, b1, Y1, N_NODES);
    spmm_csr<<<(N_NODES + 3) / 4, 256, 0, stream>>>(rowptr, ecol, ev, Y1, Hbuf, N_NODES, 1);

    // --- layer 2: Y2 = H@W2+b2 (reuse Y1 buffer) ; out = A@Y2 ---
    gemm_bias<128><<<gblocks, 256, 0, stream>>>(Hbuf, W2, b2, Y1, N_NODES);
    spmm_csr<<<(N_NODES + 3) / 4, 256, 0, stream>>>(rowptr, ecol, ev, Y1, out, N_NODES, 0);
}

// Round 2
// 635.646 us; speedup vs baseline: 1.1847x; 1.1847x over previous
//
#include <hip/hip_runtime.h>

#define N_NODES 100000
#define N_EDGES 1600000

typedef __attribute__((ext_vector_type(8))) short bf16x8;
typedef __attribute__((ext_vector_type(4))) float f32x4;

__device__ __forceinline__ unsigned int f2bf(float f) {
    unsigned int u = __float_as_uint(f);
    u += 0x7fffu + ((u >> 16) & 1u);     // RNE (inputs are finite normals)
    return u >> 16;
}

// ---------------- W transpose+convert: Wt[n][k] = bf16(W[k][n]) ----------------
__global__ __launch_bounds__(256)
void conv_w(const float* __restrict__ W, unsigned short* __restrict__ Wt, int K)
{
    int idx = blockIdx.x * 256 + threadIdx.x;
    if (idx < K * 128) {
        int k = idx >> 7, n = idx & 127;
        Wt[(size_t)n * K + k] = (unsigned short)f2bf(W[idx]);
    }
}

// ---------------- MFMA GEMM: C[M x 128] = A[M x K](fp32) @ W[K x 128] + bias ----------------
// A converted fp32->bf16 in staging; Wt is pre-converted bf16 [n][k].
// 128x128 tile, 256 threads (4 waves, 2x2), each wave 64x64 = 4x4 MFMA tiles of 16x16x32.
template<int K>
__global__ __launch_bounds__(256, 3)
void gemm_mfma(const float* __restrict__ A, const unsigned short* __restrict__ Wt,
               const float* __restrict__ bias, float* __restrict__ C, int M)
{
    constexpr int BK = 64;
    constexpr int PK = BK + 8;                 // 72 bf16 = 144 B pitch: 16B-aligned, 2-way banks max
    __shared__ unsigned short As[128 * PK];
    __shared__ unsigned short Bs[128 * PK];

    const int t    = threadIdx.x;
    const int m0   = blockIdx.x * 128;
    const int lane = t & 63;
    const int wv   = t >> 6;
    const int wm   = (wv >> 1) * 64;
    const int wn   = (wv & 1) * 64;
    const int l15  = lane & 15;
    const int quad = lane >> 4;

    f32x4 acc[4][4] = {};

    for (int k0 = 0; k0 < K; k0 += BK) {
        // stage A: 128 x 64 fp32 -> bf16. 2048 float4 slots, 8 per thread, coalesced.
        #pragma unroll
        for (int p = 0; p < 8; ++p) {
            int q  = p * 256 + t;
            int m  = q >> 4;
            int kq = (q & 15) << 2;
            int gm = m0 + m; if (gm >= M) gm = M - 1;   // clamp: dup loads, stores guarded
            float4 v = *(const float4*)(A + (size_t)gm * K + k0 + kq);
            unsigned int p0 = (f2bf(v.y) << 16) | f2bf(v.x);
            unsigned int p1 = (f2bf(v.w) << 16) | f2bf(v.z);
            *(uint2*)&As[m * PK + kq] = make_uint2(p0, p1);
        }
        // stage B: 128 rows x 64 bf16 raw copy from Wt. 1024 16B granules, 4 per thread.
        #pragma unroll
        for (int p = 0; p < 4; ++p) {
            int q = p * 256 + t;
            int n = q >> 3;
            int g = q & 7;
            int4 v = *(const int4*)(Wt + (size_t)n * K + k0 + g * 8);
            *(int4*)&Bs[n * PK + g * 8] = v;
        }
        __syncthreads();
        #pragma unroll
        for (int kk = 0; kk < BK; kk += 32) {
            bf16x8 a[4], b[4];
            #pragma unroll
            for (int i = 0; i < 4; ++i)
                a[i] = *(const bf16x8*)&As[(wm + i * 16 + l15) * PK + kk + quad * 8];
            #pragma unroll
            for (int j = 0; j < 4; ++j)
                b[j] = *(const bf16x8*)&Bs[(wn + j * 16 + l15) * PK + kk + quad * 8];
            #pragma unroll
            for (int i = 0; i < 4; ++i)
                #pragma unroll
                for (int j = 0; j < 4; ++j)
                    acc[i][j] = __builtin_amdgcn_mfma_f32_16x16x32_bf16(a[i], b[j], acc[i][j], 0, 0, 0);
        }
        __syncthreads();
    }

    // epilogue: C/D layout col = lane&15, row = quad*4 + reg
    float bv[4];
    #pragma unroll
    for (int j = 0; j < 4; ++j) bv[j] = bias[wn + j * 16 + l15];
    #pragma unroll
    for (int i = 0; i < 4; ++i) {
        #pragma unroll
        for (int r = 0; r < 4; ++r) {
            int gm = m0 + wm + i * 16 + quad * 4 + r;
            if (gm < M) {
                #pragma unroll
                for (int j = 0; j < 4; ++j)
                    C[(size_t)gm * 128 + wn + j * 16 + l15] = acc[i][j][r] + bv[j];
            }
        }
    }
}

// ---------------- CSR build ----------------
__global__ __launch_bounds__(256)
void hist_rows(const int* __restrict__ row, int* __restrict__ cnt, int E)
{
    int e = blockIdx.x * 256 + threadIdx.x;
    if (e < E) atomicAdd(&cnt[row[e]], 1);
}

__global__ __launch_bounds__(256)
void scan_a(const int* __restrict__ cnt, int* __restrict__ rowptr,
            int* __restrict__ bsum, int n)
{
    __shared__ int sd[256];
    int t = threadIdx.x;
    int base = blockIdx.x * 2048 + t * 8;
    int v[8]; int run = 0;
    #pragma unroll
    for (int j = 0; j < 8; ++j) {
        int idx = base + j;
        int c = (idx < n) ? cnt[idx] : 0;
        v[j] = run; run += c;
    }
    sd[t] = run;
    __syncthreads();
    for (int off = 1; off < 256; off <<= 1) {
        int x = (t >= off) ? sd[t - off] : 0;
        __syncthreads();
        sd[t] += x;
        __syncthreads();
    }
    int toff = sd[t] - run;
    if (t == 255) bsum[blockIdx.x] = sd[255];
    #pragma unroll
    for (int j = 0; j < 8; ++j) {
        int idx = base + j;
        if (idx < n) rowptr[idx] = toff + v[j];
    }
}

__global__ void scan_b(int* bsum, int nb)
{
    if (threadIdx.x == 0) {
        int run = 0;
        for (int i = 0; i < nb; ++i) { int x = bsum[i]; bsum[i] = run; run += x; }
    }
}

__global__ __launch_bounds__(256)
void scan_c(int* __restrict__ rowptr, const int* __restrict__ bsum,
            int* __restrict__ fill, int n, int E)
{
    int i = blockIdx.x * 256 + threadIdx.x;
    if (i < n) {
        int v = rowptr[i] + bsum[i >> 11];
        rowptr[i] = v;
        fill[i] = v;
    }
    if (i == 0) rowptr[n] = E;
}

__global__ __launch_bounds__(256)
void scatter_edges(const int* __restrict__ row, const int* __restrict__ col,
                   const float* __restrict__ vals, int* __restrict__ fill,
                   int* __restrict__ ecol, float* __restrict__ eval, int E)
{
    int e = blockIdx.x * 256 + threadIdx.x;
    if (e < E) {
        int r = row[e];
        int pos = atomicAdd(&fill[r], 1);
        ecol[pos] = col[e];
        eval[pos] = vals[e];
    }
}

// ---------------- SpMM (pull, CSR): out[i] = sum_e val_e * H[col_e] ----------------
__global__ __launch_bounds__(256)
void spmm_csr(const int* __restrict__ rowptr, const int* __restrict__ ecol,
              const float* __restrict__ eval, const float* __restrict__ H,
              float* __restrict__ out, int n, int do_relu)
{
    int wid  = (blockIdx.x * 256 + threadIdx.x) >> 6;
    int lane = threadIdx.x & 63;
    if (wid >= n) return;
    int s = rowptr[wid], e = rowptr[wid + 1];
    const float2* Hp = (const float2*)H;
    float2 acc = make_float2(0.f, 0.f);
    int p = s;
    for (; p + 2 <= e; p += 2) {
        float v0 = eval[p], v1 = eval[p + 1];
        int   c0 = ecol[p], c1 = ecol[p + 1];
        float2 h0 = Hp[(size_t)c0 * 64 + lane];
        float2 h1 = Hp[(size_t)c1 * 64 + lane];
        acc.x = fmaf(v0, h0.x, acc.x); acc.y = fmaf(v0, h0.y, acc.y);
        acc.x = fmaf(v1, h1.x, acc.x); acc.y = fmaf(v1, h1.y, acc.y);
    }
    if (p < e) {
        float v = eval[p]; int c = ecol[p];
        float2 h = Hp[(size_t)c * 64 + lane];
        acc.x = fmaf(v, h.x, acc.x); acc.y = fmaf(v, h.y, acc.y);
    }
    if (do_relu) { acc.x = fmaxf(acc.x, 0.f); acc.y = fmaxf(acc.y, 0.f); }
    ((float2*)out)[(size_t)wid * 64 + lane] = acc;
}

// ---------------- launch ----------------
extern "C" void kernel_launch(void* const* d_in, const int* in_sizes, int n_in,
                              void* d_out, int out_size, void* d_ws, size_t ws_size,
                              hipStream_t stream)
{
    const float* X    = (const float*)d_in[0];
    const float* W1   = (const float*)d_in[1];
    const float* b1   = (const float*)d_in[2];
    const float* W2   = (const float*)d_in[3];
    const float* b2   = (const float*)d_in[4];
    const float* vals = (const float*)d_in[5];
    const int*   row  = (const int*)d_in[6];
    const int*   col  = (const int*)d_in[7];
    float* out = (float*)d_out;

    char* ws = (char*)d_ws;
    size_t off = 0;
    auto alloc = [&](size_t bytes) -> void* {
        void* p = ws + off;
        off += (bytes + 511) & ~(size_t)511;
        return p;
    };
    float*          Y1     = (float*)alloc((size_t)N_NODES * 128 * 4);
    float*          Hbuf   = (float*)alloc((size_t)N_NODES * 128 * 4);
    int*            rowptr = (int*)  alloc((size_t)(N_NODES + 1) * 4);
    int*            fill   = (int*)  alloc((size_t)N_NODES * 4);
    int*            ecol   = (int*)  alloc((size_t)N_EDGES * 4);
    float*          ev     = (float*)alloc((size_t)N_EDGES * 4);
    int*            bsum   = (int*)  alloc(512);
    unsigned short* W1t    = (unsigned short*)alloc((size_t)128 * 256 * 2);
    unsigned short* W2t    = (unsigned short*)alloc((size_t)128 * 128 * 2);

    // --- weight convert+transpose (bf16) ---
    conv_w<<<(256 * 128 + 255) / 256, 256, 0, stream>>>(W1, W1t, 256);
    conv_w<<<(128 * 128 + 255) / 256, 256, 0, stream>>>(W2, W2t, 128);

    // --- CSR build ---
    hipMemsetAsync(fill, 0, (size_t)N_NODES * 4, stream);
    hist_rows<<<(N_EDGES + 255) / 256, 256, 0, stream>>>(row, fill, N_EDGES);
    const int nb = (N_NODES + 2047) / 2048;
    scan_a<<<nb, 256, 0, stream>>>(fill, rowptr, bsum, N_NODES);
    scan_b<<<1, 64, 0, stream>>>(bsum, nb);
    scan_c<<<(N_NODES + 255) / 256, 256, 0, stream>>>(rowptr, bsum, fill, N_NODES, N_EDGES);
    scatter_edges<<<(N_EDGES + 255) / 256, 256, 0, stream>>>(row, col, vals, fill, ecol, ev, N_EDGES);

    // --- layer 1: Y1 = X@W1+b1 ; H = relu(A@Y1) ---
    const int gblocks = (N_NODES + 127) / 128;
    gemm_mfma<256><<<gblocks, 256, 0, stream>>>(X, W1t, b1, Y1, N_NODES);
    spmm_csr<<<(N_NODES + 3) / 4, 256, 0, stream>>>(rowptr, ecol, ev, Y1, Hbuf, N_NODES, 1);

    // --- layer 2: Y2 = H@W2+b2 ; out = A@Y2 ---
    gemm_mfma<128><<<gblocks, 256, 0, stream>>>(Hbuf, W2t, b2, Y1, N_NODES);
    spmm_csr<<<(N_NODES + 3) / 4, 256, 0, stream>>>(rowptr, ecol, ev, Y1, out, N_NODES, 0);
}

// Round 3
// 566.053 us; speedup vs baseline: 1.3303x; 1.1229x over previous
//
#include <hip/hip_runtime.h>

#define N_NODES 100000
#define N_EDGES 1600000

typedef __attribute__((ext_vector_type(8))) short bf16x8;
typedef __attribute__((ext_vector_type(4))) float f32x4;

__device__ __forceinline__ unsigned int f2bf(float f) {
    unsigned int u = __float_as_uint(f);
    u += 0x7fffu + ((u >> 16) & 1u);     // RNE (finite normals)
    return u >> 16;
}

// ---------------- weight convert+transpose: Wt[n][k] = bf16(W[k][n]), both layers ----------------
__global__ __launch_bounds__(256)
void conv_w(const float* __restrict__ W1, const float* __restrict__ W2,
            unsigned short* __restrict__ W1t, unsigned short* __restrict__ W2t)
{
    int idx = blockIdx.x * 256 + threadIdx.x;
    if (idx < 256 * 128) {
        int k = idx >> 7, n = idx & 127;
        W1t[(size_t)n * 256 + k] = (unsigned short)f2bf(W1[idx]);
    } else if (idx < 256 * 128 + 128 * 128) {
        int j = idx - 256 * 128;
        int k = j >> 7, n = j & 127;
        W2t[(size_t)n * 128 + k] = (unsigned short)f2bf(W2[j]);
    }
}

// ---------------- MFMA GEMM: C[M x 128] = A[M x K] @ W[K x 128] + bias, C in bf16 ----------------
// ABF16: A already bf16 [M][K] (raw-copy staging); else fp32 (convert in staging).
template<int K, bool ABF16>
__global__ __launch_bounds__(256, 3)
void gemm_mfma(const void* __restrict__ Av, const unsigned short* __restrict__ Wt,
               const float* __restrict__ bias, unsigned short* __restrict__ C, int M)
{
    constexpr int BK = 64;
    constexpr int PK = BK + 8;                 // 144 B pitch: 16B-aligned, 2-way banks max (free)
    __shared__ unsigned short As[128 * PK];
    __shared__ unsigned short Bs[128 * PK];

    const int t    = threadIdx.x;
    const int m0   = blockIdx.x * 128;
    const int lane = t & 63;
    const int wv   = t >> 6;
    const int wm   = (wv >> 1) * 64;
    const int wn   = (wv & 1) * 64;
    const int l15  = lane & 15;
    const int quad = lane >> 4;

    f32x4 acc[4][4] = {};

    for (int k0 = 0; k0 < K; k0 += BK) {
        if (!ABF16) {
            const float* A = (const float*)Av;
            #pragma unroll
            for (int p = 0; p < 8; ++p) {
                int q  = p * 256 + t;
                int m  = q >> 4;
                int kq = (q & 15) << 2;
                int gm = m0 + m; if (gm >= M) gm = M - 1;
                float4 v = *(const float4*)(A + (size_t)gm * K + k0 + kq);
                unsigned int p0 = (f2bf(v.y) << 16) | f2bf(v.x);
                unsigned int p1 = (f2bf(v.w) << 16) | f2bf(v.z);
                *(uint2*)&As[m * PK + kq] = make_uint2(p0, p1);
            }
        } else {
            const unsigned short* A = (const unsigned short*)Av;
            #pragma unroll
            for (int p = 0; p < 4; ++p) {
                int q = p * 256 + t;
                int m = q >> 3;
                int g = q & 7;
                int gm = m0 + m; if (gm >= M) gm = M - 1;
                int4 v = *(const int4*)(A + (size_t)gm * K + k0 + g * 8);
                *(int4*)&As[m * PK + g * 8] = v;
            }
        }
        #pragma unroll
        for (int p = 0; p < 4; ++p) {
            int q = p * 256 + t;
            int n = q >> 3;
            int g = q & 7;
            int4 v = *(const int4*)(Wt + (size_t)n * K + k0 + g * 8);
            *(int4*)&Bs[n * PK + g * 8] = v;
        }
        __syncthreads();
        #pragma unroll
        for (int kk = 0; kk < BK; kk += 32) {
            bf16x8 a[4], b[4];
            #pragma unroll
            for (int i = 0; i < 4; ++i)
                a[i] = *(const bf16x8*)&As[(wm + i * 16 + l15) * PK + kk + quad * 8];
            #pragma unroll
            for (int j = 0; j < 4; ++j)
                b[j] = *(const bf16x8*)&Bs[(wn + j * 16 + l15) * PK + kk + quad * 8];
            #pragma unroll
            for (int i = 0; i < 4; ++i)
                #pragma unroll
                for (int j = 0; j < 4; ++j)
                    acc[i][j] = __builtin_amdgcn_mfma_f32_16x16x32_bf16(a[i], b[j], acc[i][j], 0, 0, 0);
        }
        __syncthreads();
    }

    // epilogue: C/D layout col = lane&15, row = quad*4 + reg; store bf16
    float bv[4];
    #pragma unroll
    for (int j = 0; j < 4; ++j) bv[j] = bias[wn + j * 16 + l15];
    #pragma unroll
    for (int i = 0; i < 4; ++i) {
        #pragma unroll
        for (int r = 0; r < 4; ++r) {
            int gm = m0 + wm + i * 16 + quad * 4 + r;
            if (gm < M) {
                #pragma unroll
                for (int j = 0; j < 4; ++j)
                    C[(size_t)gm * 128 + wn + j * 16 + l15] =
                        (unsigned short)f2bf(acc[i][j][r] + bv[j]);
            }
        }
    }
}

// ---------------- CSR build ----------------
__global__ __launch_bounds__(256)
void hist_rows(const int* __restrict__ row, int* __restrict__ cnt, int E)
{
    int e = blockIdx.x * 256 + threadIdx.x;
    if (e < E) atomicAdd(&cnt[row[e]], 1);
}

__global__ __launch_bounds__(256)
void scan_a(const int* __restrict__ cnt, int* __restrict__ rowptr,
            int* __restrict__ bsum, int n)
{
    __shared__ int sd[256];
    int t = threadIdx.x;
    int base = blockIdx.x * 2048 + t * 8;
    int v[8]; int run = 0;
    #pragma unroll
    for (int j = 0; j < 8; ++j) {
        int idx = base + j;
        int c = (idx < n) ? cnt[idx] : 0;
        v[j] = run; run += c;
    }
    sd[t] = run;
    __syncthreads();
    for (int off = 1; off < 256; off <<= 1) {
        int x = (t >= off) ? sd[t - off] : 0;
        __syncthreads();
        sd[t] += x;
        __syncthreads();
    }
    int toff = sd[t] - run;
    if (t == 255) bsum[blockIdx.x] = sd[255];
    #pragma unroll
    for (int j = 0; j < 8; ++j) {
        int idx = base + j;
        if (idx < n) rowptr[idx] = toff + v[j];
    }
}

// adds block-prefix of bsum (computed in-kernel: nb<=64) and inits fill cursors
__global__ __launch_bounds__(256)
void scan_c(int* __restrict__ rowptr, const int* __restrict__ bsum,
            int* __restrict__ fill, int n, int E, int nb)
{
    __shared__ int s_off;
    int i = blockIdx.x * 256 + threadIdx.x;
    int blk = blockIdx.x >> 3;                 // = i>>11 (256*8 = 2048)
    if (threadIdx.x < 64) {
        int t = threadIdx.x;
        int v = (t < nb) ? bsum[t] : 0;
        #pragma unroll
        for (int o = 1; o < 64; o <<= 1) {
            int u = __shfl_up(v, o, 64);
            if (t >= o) v += u;
        }
        int ex = (blk > 0) ? __shfl(v, blk - 1, 64) : 0;
        if (t == 0) s_off = ex;
    }
    __syncthreads();
    int off = s_off;
    if (i < n) {
        int v = rowptr[i] + off;
        rowptr[i] = v;
        fill[i] = v;
    }
    if (i == 0) rowptr[n] = E;
}

// row-range pass: confine scattered writes to a small window (L2-resident, full-line fill)
__global__ __launch_bounds__(256)
void scatter_pass(const int* __restrict__ row, const int* __restrict__ col,
                  const float* __restrict__ vals, int* __restrict__ fill,
                  int2* __restrict__ ep, int E, int lo, int hi)
{
    int e = blockIdx.x * 256 + threadIdx.x;
    if (e < E) {
        int r = row[e];
        if (r >= lo && r < hi) {
            int pos = atomicAdd(&fill[r], 1);
            ep[pos] = make_int2(col[e], __float_as_int(vals[e]));
        }
    }
}

// ---------------- SpMM (pull, CSR, bf16 H): out[i] = sum_e val_e * H[col_e] ----------------
// one wave per node; 64 lanes x uint(2 bf16) = 256B row
template<bool RELU, bool OUTBF16>
__global__ __launch_bounds__(256)
void spmm_csr(const int* __restrict__ rowptr, const int2* __restrict__ ep,
              const unsigned int* __restrict__ H, void* __restrict__ outv, int n)
{
    int wid  = (blockIdx.x * 256 + threadIdx.x) >> 6;
    int lane = threadIdx.x & 63;
    if (wid >= n) return;
    int s = rowptr[wid], e = rowptr[wid + 1];
    float ax = 0.f, ay = 0.f;
    int p = s;
    for (; p + 2 <= e; p += 2) {
        int2 e0 = ep[p], e1 = ep[p + 1];
        unsigned int h0 = H[(size_t)e0.x * 64 + lane];
        unsigned int h1 = H[(size_t)e1.x * 64 + lane];
        float v0 = __int_as_float(e0.y), v1 = __int_as_float(e1.y);
        ax = fmaf(v0, __uint_as_float(h0 << 16), ax);
        ay = fmaf(v0, __uint_as_float(h0 & 0xffff0000u), ay);
        ax = fmaf(v1, __uint_as_float(h1 << 16), ax);
        ay = fmaf(v1, __uint_as_float(h1 & 0xffff0000u), ay);
    }
    if (p < e) {
        int2 e0 = ep[p];
        unsigned int h0 = H[(size_t)e0.x * 64 + lane];
        float v0 = __int_as_float(e0.y);
        ax = fmaf(v0, __uint_as_float(h0 << 16), ax);
        ay = fmaf(v0, __uint_as_float(h0 & 0xffff0000u), ay);
    }
    if (RELU) { ax = fmaxf(ax, 0.f); ay = fmaxf(ay, 0.f); }
    if (OUTBF16) {
        ((unsigned int*)outv)[(size_t)wid * 64 + lane] = (f2bf(ay) << 16) | f2bf(ax);
    } else {
        ((float2*)outv)[(size_t)wid * 64 + lane] = make_float2(ax, ay);
    }
}

// ---------------- launch ----------------
extern "C" void kernel_launch(void* const* d_in, const int* in_sizes, int n_in,
                              void* d_out, int out_size, void* d_ws, size_t ws_size,
                              hipStream_t stream)
{
    const float* X    = (const float*)d_in[0];
    const float* W1   = (const float*)d_in[1];
    const float* b1   = (const float*)d_in[2];
    const float* W2   = (const float*)d_in[3];
    const float* b2   = (const float*)d_in[4];
    const float* vals = (const float*)d_in[5];
    const int*   row  = (const int*)d_in[6];
    const int*   col  = (const int*)d_in[7];
    float* out = (float*)d_out;

    char* ws = (char*)d_ws;
    size_t off = 0;
    auto alloc = [&](size_t bytes) -> void* {
        void* p = ws + off;
        off += (bytes + 511) & ~(size_t)511;
        return p;
    };
    unsigned short* Y1     = (unsigned short*)alloc((size_t)N_NODES * 128 * 2); // bf16 Y1/Y2
    unsigned short* Hbuf   = (unsigned short*)alloc((size_t)N_NODES * 128 * 2); // bf16 relu(spmm1)
    int*            rowptr = (int*)  alloc((size_t)(N_NODES + 1) * 4);
    int*            fill   = (int*)  alloc((size_t)N_NODES * 4);
    int2*           ep     = (int2*) alloc((size_t)N_EDGES * 8);
    int*            bsum   = (int*)  alloc(512);
    unsigned short* W1t    = (unsigned short*)alloc((size_t)128 * 256 * 2);
    unsigned short* W2t    = (unsigned short*)alloc((size_t)128 * 128 * 2);

    // --- weight convert+transpose (bf16), single launch ---
    conv_w<<<(256 * 128 + 128 * 128 + 255) / 256, 256, 0, stream>>>(W1, W2, W1t, W2t);

    // --- CSR build ---
    hipMemsetAsync(fill, 0, (size_t)N_NODES * 4, stream);
    hist_rows<<<(N_EDGES + 255) / 256, 256, 0, stream>>>(row, fill, N_EDGES);
    const int nb = (N_NODES + 2047) / 2048; // 49
    scan_a<<<nb, 256, 0, stream>>>(fill, rowptr, bsum, N_NODES);
    scan_c<<<(N_NODES + 255) / 256, 256, 0, stream>>>(rowptr, bsum, fill, N_NODES, N_EDGES, nb);
    const int egrid = (N_EDGES + 255) / 256;
    const int rchunk = (N_NODES + 3) / 4;   // 4 row-range passes
    for (int p = 0; p < 4; ++p)
        scatter_pass<<<egrid, 256, 0, stream>>>(row, col, vals, fill, ep, N_EDGES,
                                                p * rchunk, (p + 1) * rchunk);

    // --- layer 1: Y1 = bf16(X@W1+b1) ; H = bf16(relu(A@Y1)) ---
    const int gblocks = (N_NODES + 127) / 128;
    gemm_mfma<256, false><<<gblocks, 256, 0, stream>>>(X, W1t, b1, Y1, N_NODES);
    spmm_csr<true, true><<<(N_NODES + 3) / 4, 256, 0, stream>>>(rowptr, ep, (const unsigned int*)Y1, Hbuf, N_NODES);

    // --- layer 2: Y2 = bf16(H@W2+b2) ; out = A@Y2 (fp32) ---
    gemm_mfma<128, true><<<gblocks, 256, 0, stream>>>(Hbuf, W2t, b2, Y1, N_NODES);
    spmm_csr<false, false><<<(N_NODES + 3) / 4, 256, 0, stream>>>(rowptr, ep, (const unsigned int*)Y1, out, N_NODES);
}